// Round 1
// 2741.096 us; speedup vs baseline: 1.1224x; 1.1224x over previous
//
#include <hip/hip_runtime.h>
#include <hip/hip_bf16.h>
#include <stdint.h>

#define VOCAB 8192
#define HIDDEN 1024
#define BATCH 64
#define SEQ 256

#define NPROD 64      // recurrence workgroups (barrier participants)
#define NCONS 192     // GEMM consumer workgroups
#define GBM 128
#define GBN 128
#define GBK 32
#define NT_M ((SEQ * BATCH) / GBM)   // 128 row-blocks, 2 timesteps each
#define NT_N (VOCAB / GBN)           // 64

typedef __attribute__((ext_vector_type(8))) short short8;
typedef __attribute__((ext_vector_type(4))) float floatx4;

__device__ __forceinline__ short f2bf(float x) {
    __hip_bfloat16 h = __float2bfloat16(x);
    return *reinterpret_cast<short*>(&h);
}

// async global->LDS, 16B per lane. LDS dest must equal (wave-uniform base + lane*16).
__device__ __forceinline__ void load_lds16(const void* g, void* l) {
    __builtin_amdgcn_global_load_lds(
        (const __attribute__((address_space(1))) void*)(uintptr_t)g,
        (__attribute__((address_space(3))) void*)(uint32_t)(uintptr_t)l,
        16, 0, 0);
}

// ---------------- prep kernels ----------------

__global__ void cast_h0(const float* __restrict__ s, short* __restrict__ d) {
    int i = blockIdx.x * 256 + threadIdx.x;
    d[i] = f2bf(s[i]);
}

// w_ho (1024 x 8192 fp32 row-major) -> whoT (8192 x 1024 bf16 row-major)
__global__ void transpose_cast(const float* __restrict__ who, short* __restrict__ whoT) {
    __shared__ float tile[32][33];
    int n0 = blockIdx.x * 32;   // along VOCAB
    int k0 = blockIdx.y * 32;   // along HIDDEN
    for (int r = threadIdx.y; r < 32; r += 8)
        tile[r][threadIdx.x] = who[(size_t)(k0 + r) * VOCAB + n0 + threadIdx.x];
    __syncthreads();
    for (int r = threadIdx.y; r < 32; r += 8)
        whoT[(size_t)(n0 + r) * HIDDEN + k0 + threadIdx.x] = f2bf(tile[threadIdx.x][r]);
}

// ---------------- fused persistent kernel ----------------
// wgs [0,64):  recurrence producers (identical structure to previous round,
//              plus xe gather software-pipelined one step ahead so the serial
//              X -> w_xh chain hides under the barrier wait).
// wgs [64,256): output-GEMM consumers. Tile (ti,tj) of C needs Hall slabs
//              2ti+1, 2ti+2, i.e. bar >= 64*(2ti+2). wg0 mirrors the barrier
//              count into `prog` (separate cacheline) so consumer polling
//              doesn't contend with producer arrivals. Consumers acquire-fence
//              only when they actually had to wait; first touch of any Hall
//              slab is always post-release so no stale line can exist.
__global__ __launch_bounds__(256) void rnn_fused(
    short* __restrict__ Hall,              // (SEQ+1, 64, 1024) bf16
    const float* __restrict__ w_hh, const float* __restrict__ w_xh,
    const float* __restrict__ b_h, const int* __restrict__ X,
    float* __restrict__ hfin, int* bar, int* prog,
    const short* __restrict__ whoT, const float* __restrict__ b_o,
    float* __restrict__ C) {
    __shared__ __align__(16) short smem[16 * 1032];  // 33 KB union
    const int tid = threadIdx.x;

    if (blockIdx.x < NPROD) {
        // ================= producer: h recurrence =================
        short* Bs = smem;
        const int g = blockIdx.x;
        const int w = tid >> 6, lane = tid & 63;
        const int q = lane >> 4, r15 = lane & 15;

        // stage w_hh slice once: Bs[c][k] = bf16(w_hh[k][16g+c])
        for (int idx = tid; idx < 16 * 1024; idx += 256) {
            int c = idx & 15, k = idx >> 4;
            Bs[c * 1032 + k] = f2bf(w_hh[(size_t)k * HIDDEN + g * 16 + c]);
        }
        __syncthreads();

        const int jcol = g * 16 + r15;
        const float bh = b_h[jcol];
        int brow[4];
#pragma unroll
        for (int r = 0; r < 4; r++) brow[r] = w * 16 + q * 4 + r;
        const int afr_off = (w * 16 + r15) * HIDDEN + q * 8;

        // xe pipeline: xe = gather for step t; xr = X indices for step t+1
        int xr[4];
#pragma unroll
        for (int r = 0; r < 4; r++) xr[r] = X[brow[r] * SEQ];
        float xe[4];
#pragma unroll
        for (int r = 0; r < 4; r++) xe[r] = w_xh[(size_t)xr[r] * HIDDEN + jcol];
#pragma unroll
        for (int r = 0; r < 4; r++) xr[r] = X[brow[r] * SEQ + 1];

        for (int t = 0; t < SEQ; t++) {
            const short* Ab = Hall + (size_t)t * (BATCH * HIDDEN) + afr_off;
            floatx4 a0 = {0.f, 0.f, 0.f, 0.f}, a1 = a0, a2 = a0, a3 = a0;
#pragma unroll
            for (int k0 = 0; k0 < HIDDEN; k0 += 128) {
                short8 f0 = *(const short8*)(Ab + k0);
                short8 f1 = *(const short8*)(Ab + k0 + 32);
                short8 f2 = *(const short8*)(Ab + k0 + 64);
                short8 f3 = *(const short8*)(Ab + k0 + 96);
                const short* Bb = &Bs[r15 * 1032 + k0 + q * 8];
                short8 b0 = *(const short8*)(Bb);
                short8 b1 = *(const short8*)(Bb + 32);
                short8 b2 = *(const short8*)(Bb + 64);
                short8 b3 = *(const short8*)(Bb + 96);
                a0 = __builtin_amdgcn_mfma_f32_16x16x32_bf16(f0, b0, a0, 0, 0, 0);
                a1 = __builtin_amdgcn_mfma_f32_16x16x32_bf16(f1, b1, a1, 0, 0, 0);
                a2 = __builtin_amdgcn_mfma_f32_16x16x32_bf16(f2, b2, a2, 0, 0, 0);
                a3 = __builtin_amdgcn_mfma_f32_16x16x32_bf16(f3, b3, a3, 0, 0, 0);
            }
            floatx4 acc = (a0 + a1) + (a2 + a3);

            short* Hnext = Hall + (size_t)(t + 1) * (BATCH * HIDDEN);
#pragma unroll
            for (int r = 0; r < 4; r++) {
                float v = acc[r] + xe[r] + bh;
                float h = tanhf(v);
                Hnext[brow[r] * HIDDEN + jcol] = f2bf(h);
                if (t == SEQ - 1) hfin[brow[r] * HIDDEN + jcol] = h;
            }

            // prefetch next step's xe (and t+2's X indices) under the barrier
            float xen[4];
            if (t + 1 < SEQ) {
#pragma unroll
                for (int r = 0; r < 4; r++) xen[r] = w_xh[(size_t)xr[r] * HIDDEN + jcol];
                if (t + 2 < SEQ) {
#pragma unroll
                    for (int r = 0; r < 4; r++) xr[r] = X[brow[r] * SEQ + t + 2];
                }
            }

            // grid barrier across producers: release -> count -> poll -> acquire
            __syncthreads();
            if (tid == 0) {
                __builtin_amdgcn_fence(__ATOMIC_RELEASE, "agent");
                __hip_atomic_fetch_add(bar, 1, __ATOMIC_RELAXED, __HIP_MEMORY_SCOPE_AGENT);
                const int target = NPROD * (t + 1);
                while (__hip_atomic_load(bar, __ATOMIC_RELAXED, __HIP_MEMORY_SCOPE_AGENT) < target)
                    __builtin_amdgcn_s_sleep(1);
                __builtin_amdgcn_fence(__ATOMIC_ACQUIRE, "agent");
                if (g == 0)  // mirror progress for consumers (separate cacheline)
                    __hip_atomic_store(prog, target, __ATOMIC_RELAXED, __HIP_MEMORY_SCOPE_AGENT);
            }
            __syncthreads();
#pragma unroll
            for (int r = 0; r < 4; r++) xe[r] = xen[r];
        }
    } else {
        // ================= consumer: C = Hall[1:] @ whoT^T + b_o =================
        short* la = smem;                 // 128x32 bf16 (8 KB)
        short* lb = smem + GBM * GBK;     // 128x32 bf16 (8 KB)
        const short* __restrict__ A = Hall + BATCH * HIDDEN;
        const int cid = (int)blockIdx.x - NPROD;
        const int wave = tid >> 6, lane = tid & 63;
        const int wm = (wave >> 1) * 64, wn = (wave & 1) * 64;
        const int q = lane >> 4, r15 = lane & 15;
        const int col_l = lane & 15, row_q = (lane >> 4) * 4;

        // stride-NCONS over tiles in row-major (ti,tj): each wg keeps tj fixed
        // (B-panel reuse) and walks ti by +3, so `needed` grows monotonically.
        for (int n = cid; n < NT_M * NT_N; n += NCONS) {
            const int ti = n / NT_N, tj = n - ti * NT_N;
            const int m0 = ti * GBM, n0 = tj * GBN;

            if (tid == 0) {
                const int needed = NPROD * (2 * ti + 2);
                if (__hip_atomic_load(prog, __ATOMIC_RELAXED, __HIP_MEMORY_SCOPE_AGENT) < needed) {
                    while (__hip_atomic_load(prog, __ATOMIC_RELAXED, __HIP_MEMORY_SCOPE_AGENT) < needed)
                        __builtin_amdgcn_s_sleep(2);
                    __builtin_amdgcn_fence(__ATOMIC_ACQUIRE, "agent");
                }
            }
            __syncthreads();

            floatx4 acc[4][4] = {};
            for (int k0 = 0; k0 < HIDDEN; k0 += GBK) {
#pragma unroll
                for (int i = 0; i < 2; i++) {
                    int c = wave * 128 + i * 64 + lane;   // LDS dest = base + lane*16
                    int row = c >> 2, s = c & 3;
                    int gq = s ^ ((row >> 1) & 3);
                    load_lds16(&A[(size_t)(m0 + row) * HIDDEN + k0 + gq * 8], &la[c * 8]);
                    load_lds16(&whoT[(size_t)(n0 + row) * HIDDEN + k0 + gq * 8], &lb[c * 8]);
                }
                __syncthreads();

                short8 af[4], bf[4];
#pragma unroll
                for (int i = 0; i < 4; i++) {
                    int ra = wm + i * 16 + r15;
                    af[i] = *(const short8*)&la[ra * GBK + (q ^ ((ra >> 1) & 3)) * 8];
                    int rb = wn + i * 16 + r15;
                    bf[i] = *(const short8*)&lb[rb * GBK + (q ^ ((rb >> 1) & 3)) * 8];
                }
#pragma unroll
                for (int i = 0; i < 4; i++)
#pragma unroll
                    for (int jj = 0; jj < 4; jj++)
                        acc[i][jj] = __builtin_amdgcn_mfma_f32_16x16x32_bf16(af[i], bf[jj], acc[i][jj], 0, 0, 0);
                __syncthreads();
            }

#pragma unroll
            for (int i = 0; i < 4; i++) {
#pragma unroll
                for (int jj = 0; jj < 4; jj++) {
                    int col = n0 + wn + jj * 16 + col_l;
                    float bb = b_o[col];
#pragma unroll
                    for (int r = 0; r < 4; r++) {
                        int row = m0 + wm + i * 16 + row_q + r;
                        // nt store: keep C out of L2 so producer release fences
                        // don't wait on consumer dirty lines
                        __builtin_nontemporal_store(acc[i][jj][r] + bb,
                                                    &C[(size_t)row * VOCAB + col]);
                    }
                }
            }
        }
    }
}

// ---------------- launch ----------------

extern "C" void kernel_launch(void* const* d_in, const int* in_sizes, int n_in,
                              void* d_out, int out_size, void* d_ws, size_t ws_size,
                              hipStream_t stream) {
    const int*   X      = (const int*)d_in[0];
    const float* status = (const float*)d_in[1];
    const float* w_xh   = (const float*)d_in[2];
    const float* w_hh   = (const float*)d_in[3];
    const float* w_ho   = (const float*)d_in[4];
    const float* b_h    = (const float*)d_in[5];
    const float* b_o    = (const float*)d_in[6];
    float* out = (float*)d_out;

    char* ws = (char*)d_ws;
    int*   bar  = (int*)ws;                                    // cacheline 0
    int*   prog = (int*)(ws + 128);                            // separate cacheline
    short* Hall = (short*)(ws + 4096);                         // (257,64,1024) bf16 = 33.7 MB
    short* whoT = (short*)(ws + 4096 + (size_t)(SEQ + 1) * BATCH * HIDDEN * 2);  // 16 MB

    hipMemsetAsync(ws, 0, 256, stream);
    cast_h0<<<BATCH * HIDDEN / 256, 256, 0, stream>>>(status, Hall);
    transpose_cast<<<dim3(VOCAB / 32, HIDDEN / 32), dim3(32, 8), 0, stream>>>(w_ho, whoT);

    rnn_fused<<<NPROD + NCONS, 256, 0, stream>>>(
        Hall, w_hh, w_xh, b_h, X,
        out + (size_t)SEQ * BATCH * VOCAB,   // h_final slot after Y
        bar, prog, whoT, b_o, out);
}

// Round 2
// 2430.161 us; speedup vs baseline: 1.2661x; 1.1279x over previous
//
#include <hip/hip_runtime.h>
#include <hip/hip_bf16.h>
#include <stdint.h>

#define VOCAB 8192
#define HIDDEN 1024
#define BATCH 64
#define SEQ 256

#define NPROD 64      // recurrence workgroups (barrier participants)
#define NCONS 192     // GEMM consumer workgroups
#define GBM 128
#define GBN 128
#define GBK 32
#define NT_M ((SEQ * BATCH) / GBM)   // 128 row-blocks, 2 timesteps each
#define NT_N (VOCAB / GBN)           // 64

typedef __attribute__((ext_vector_type(8))) short short8;
typedef __attribute__((ext_vector_type(4))) float floatx4;

__device__ __forceinline__ short f2bf(float x) {
    __hip_bfloat16 h = __float2bfloat16(x);
    return *reinterpret_cast<short*>(&h);
}

// async global->LDS, 16B per lane. LDS dest must equal (wave-uniform base + lane*16).
__device__ __forceinline__ void load_lds16(const void* g, void* l) {
    __builtin_amdgcn_global_load_lds(
        (const __attribute__((address_space(1))) void*)(uintptr_t)g,
        (__attribute__((address_space(3))) void*)(uint32_t)(uintptr_t)l,
        16, 0, 0);
}

// agent-scope relaxed store: global_store_short sc1 — write-through to L3
// (point of agent coherence), bypassing/updating L2 coherently. Combined with a
// per-wave vmcnt(0) drain before the barrier arrive, this replaces the
// release fence's buffer_wbl2. No reader can hold a stale L2 line because
// every Hall address is written exactly once before its first read.
__device__ __forceinline__ void st_h(short* p, short v) {
    __hip_atomic_store(p, v, __ATOMIC_RELAXED, __HIP_MEMORY_SCOPE_AGENT);
}

// ---------------- prep kernels ----------------

__global__ void cast_h0(const float* __restrict__ s, short* __restrict__ d) {
    int i = blockIdx.x * 256 + threadIdx.x;
    d[i] = f2bf(s[i]);
}

// w_ho (1024 x 8192 fp32 row-major) -> whoT (8192 x 1024 bf16 row-major)
__global__ void transpose_cast(const float* __restrict__ who, short* __restrict__ whoT) {
    __shared__ float tile[32][33];
    int n0 = blockIdx.x * 32;   // along VOCAB
    int k0 = blockIdx.y * 32;   // along HIDDEN
    for (int r = threadIdx.y; r < 32; r += 8)
        tile[r][threadIdx.x] = who[(size_t)(k0 + r) * VOCAB + n0 + threadIdx.x];
    __syncthreads();
    for (int r = threadIdx.y; r < 32; r += 8)
        whoT[(size_t)(n0 + r) * HIDDEN + k0 + threadIdx.x] = f2bf(tile[threadIdx.x][r]);
}

// ---------------- fused persistent kernel ----------------
// wgs [0,64):  recurrence producers. NO agent fences: h-stores are sc1
//              write-through atomics, each wave drains vmcnt(0) before the
//              arrive, readers use plain cached loads (never stale — each Hall
//              address is single-writer, written before first read).
// wgs [64,256): output-GEMM consumers, paced by the mirrored progress word.
//              With no buffer_inv anywhere, whoT B-panels and Hall A-slabs
//              stay L2-resident.
__global__ __launch_bounds__(256) void rnn_fused(
    short* __restrict__ Hall,              // (SEQ+1, 64, 1024) bf16
    const float* __restrict__ w_hh, const float* __restrict__ w_xh,
    const float* __restrict__ b_h, const int* __restrict__ X,
    float* __restrict__ hfin, int* bar, int* prog,
    const short* __restrict__ whoT, const float* __restrict__ b_o,
    float* __restrict__ C) {
    __shared__ __align__(16) short smem[16 * 1032];  // 33 KB union
    const int tid = threadIdx.x;

    if (blockIdx.x < NPROD) {
        // ================= producer: h recurrence =================
        short* Bs = smem;
        const int g = blockIdx.x;
        const int w = tid >> 6, lane = tid & 63;
        const int q = lane >> 4, r15 = lane & 15;

        // stage w_hh slice once: Bs[c][k] = bf16(w_hh[k][16g+c])
        for (int idx = tid; idx < 16 * 1024; idx += 256) {
            int c = idx & 15, k = idx >> 4;
            Bs[c * 1032 + k] = f2bf(w_hh[(size_t)k * HIDDEN + g * 16 + c]);
        }
        __syncthreads();

        const int jcol = g * 16 + r15;
        const float bh = b_h[jcol];
        int brow[4];
#pragma unroll
        for (int r = 0; r < 4; r++) brow[r] = w * 16 + q * 4 + r;
        const int afr_off = (w * 16 + r15) * HIDDEN + q * 8;

        // xe pipeline: xe = gather for step 0; xr = X indices for step 1
        int xr[4];
#pragma unroll
        for (int r = 0; r < 4; r++) xr[r] = X[brow[r] * SEQ];
        float xe[4];
#pragma unroll
        for (int r = 0; r < 4; r++) xe[r] = w_xh[(size_t)xr[r] * HIDDEN + jcol];
#pragma unroll
        for (int r = 0; r < 4; r++) xr[r] = X[brow[r] * SEQ + 1];

        for (int t = 0; t < SEQ; t++) {
            // issue next step's xe gather FIRST: its HBM latency hides under
            // the MFMA loop instead of delaying the barrier arrive.
            float xen[4];
            if (t + 1 < SEQ) {
#pragma unroll
                for (int r = 0; r < 4; r++) xen[r] = w_xh[(size_t)xr[r] * HIDDEN + jcol];
                if (t + 2 < SEQ) {
#pragma unroll
                    for (int r = 0; r < 4; r++) xr[r] = X[brow[r] * SEQ + t + 2];
                }
            }

            const short* Ab = Hall + (size_t)t * (BATCH * HIDDEN) + afr_off;
            floatx4 a0 = {0.f, 0.f, 0.f, 0.f}, a1 = a0, a2 = a0, a3 = a0;
#pragma unroll
            for (int k0 = 0; k0 < HIDDEN; k0 += 128) {
                short8 f0 = *(const short8*)(Ab + k0);
                short8 f1 = *(const short8*)(Ab + k0 + 32);
                short8 f2 = *(const short8*)(Ab + k0 + 64);
                short8 f3 = *(const short8*)(Ab + k0 + 96);
                const short* Bb = &Bs[r15 * 1032 + k0 + q * 8];
                short8 b0 = *(const short8*)(Bb);
                short8 b1 = *(const short8*)(Bb + 32);
                short8 b2 = *(const short8*)(Bb + 64);
                short8 b3 = *(const short8*)(Bb + 96);
                a0 = __builtin_amdgcn_mfma_f32_16x16x32_bf16(f0, b0, a0, 0, 0, 0);
                a1 = __builtin_amdgcn_mfma_f32_16x16x32_bf16(f1, b1, a1, 0, 0, 0);
                a2 = __builtin_amdgcn_mfma_f32_16x16x32_bf16(f2, b2, a2, 0, 0, 0);
                a3 = __builtin_amdgcn_mfma_f32_16x16x32_bf16(f3, b3, a3, 0, 0, 0);
            }
            floatx4 acc = (a0 + a1) + (a2 + a3);

            short* Hnext = Hall + (size_t)(t + 1) * (BATCH * HIDDEN);
#pragma unroll
            for (int r = 0; r < 4; r++) {
                float v = acc[r] + xe[r] + bh;
                float h = tanhf(v);
                st_h(&Hnext[brow[r] * HIDDEN + jcol], f2bf(h));
                if (t == SEQ - 1) hfin[brow[r] * HIDDEN + jcol] = h;
            }

            // every wave drains its sc1 stores to L3 before the wg arrives
            asm volatile("s_waitcnt vmcnt(0)" ::: "memory");
            __syncthreads();
            if (tid == 0) {
                __hip_atomic_fetch_add(bar, 1, __ATOMIC_RELAXED, __HIP_MEMORY_SCOPE_AGENT);
                const int target = NPROD * (t + 1);
                while (__hip_atomic_load(bar, __ATOMIC_RELAXED, __HIP_MEMORY_SCOPE_AGENT) < target)
                    __builtin_amdgcn_s_sleep(1);
                if (g == 0)  // mirror progress for consumers (separate cacheline)
                    __hip_atomic_store(prog, target, __ATOMIC_RELAXED, __HIP_MEMORY_SCOPE_AGENT);
            }
            __syncthreads();
            // workgroup-scope acquire: compiler ordering only, no cache ops
            __builtin_amdgcn_fence(__ATOMIC_ACQUIRE, "workgroup");
#pragma unroll
            for (int r = 0; r < 4; r++) xe[r] = xen[r];
        }
    } else {
        // ================= consumer: C = Hall[1:] @ whoT^T + b_o =================
        short* la = smem;                 // 128x32 bf16 (8 KB)
        short* lb = smem + GBM * GBK;     // 128x32 bf16 (8 KB)
        const short* __restrict__ A = Hall + BATCH * HIDDEN;
        const int cid = (int)blockIdx.x - NPROD;
        const int wave = tid >> 6, lane = tid & 63;
        const int wm = (wave >> 1) * 64, wn = (wave & 1) * 64;
        const int q = lane >> 4, r15 = lane & 15;
        const int col_l = lane & 15, row_q = (lane >> 4) * 4;

        // stride-NCONS over tiles row-major: `needed` grows monotonically.
        for (int n = cid; n < NT_M * NT_N; n += NCONS) {
            const int ti = n / NT_N, tj = n - ti * NT_N;
            const int m0 = ti * GBM, n0 = tj * GBN;

            if (tid == 0) {
                const int needed = NPROD * (2 * ti + 2);
                while (__hip_atomic_load(prog, __ATOMIC_RELAXED, __HIP_MEMORY_SCOPE_AGENT) < needed)
                    __builtin_amdgcn_s_sleep(2);
            }
            __syncthreads();
            __builtin_amdgcn_fence(__ATOMIC_ACQUIRE, "workgroup");

            floatx4 acc[4][4] = {};
            for (int k0 = 0; k0 < HIDDEN; k0 += GBK) {
#pragma unroll
                for (int i = 0; i < 2; i++) {
                    int c = wave * 128 + i * 64 + lane;   // LDS dest = base + lane*16
                    int row = c >> 2, s = c & 3;
                    int gq = s ^ ((row >> 1) & 3);
                    load_lds16(&A[(size_t)(m0 + row) * HIDDEN + k0 + gq * 8], &la[c * 8]);
                    load_lds16(&whoT[(size_t)(n0 + row) * HIDDEN + k0 + gq * 8], &lb[c * 8]);
                }
                __syncthreads();

                short8 af[4], bf[4];
#pragma unroll
                for (int i = 0; i < 4; i++) {
                    int ra = wm + i * 16 + r15;
                    af[i] = *(const short8*)&la[ra * GBK + (q ^ ((ra >> 1) & 3)) * 8];
                    int rb = wn + i * 16 + r15;
                    bf[i] = *(const short8*)&lb[rb * GBK + (q ^ ((rb >> 1) & 3)) * 8];
                }
#pragma unroll
                for (int i = 0; i < 4; i++)
#pragma unroll
                    for (int jj = 0; jj < 4; jj++)
                        acc[i][jj] = __builtin_amdgcn_mfma_f32_16x16x32_bf16(af[i], bf[jj], acc[i][jj], 0, 0, 0);
                __syncthreads();
            }

#pragma unroll
            for (int i = 0; i < 4; i++) {
#pragma unroll
                for (int jj = 0; jj < 4; jj++) {
                    int col = n0 + wn + jj * 16 + col_l;
                    float bb = b_o[col];
#pragma unroll
                    for (int r = 0; r < 4; r++) {
                        int row = m0 + wm + i * 16 + row_q + r;
                        // nt store: keep C out of L2
                        __builtin_nontemporal_store(acc[i][jj][r] + bb,
                                                    &C[(size_t)row * VOCAB + col]);
                    }
                }
            }
        }
    }
}

// ---------------- launch ----------------

extern "C" void kernel_launch(void* const* d_in, const int* in_sizes, int n_in,
                              void* d_out, int out_size, void* d_ws, size_t ws_size,
                              hipStream_t stream) {
    const int*   X      = (const int*)d_in[0];
    const float* status = (const float*)d_in[1];
    const float* w_xh   = (const float*)d_in[2];
    const float* w_hh   = (const float*)d_in[3];
    const float* w_ho   = (const float*)d_in[4];
    const float* b_h    = (const float*)d_in[5];
    const float* b_o    = (const float*)d_in[6];
    float* out = (float*)d_out;

    char* ws = (char*)d_ws;
    int*   bar  = (int*)ws;                                    // cacheline 0
    int*   prog = (int*)(ws + 128);                            // separate cacheline
    short* Hall = (short*)(ws + 4096);                         // (257,64,1024) bf16 = 33.7 MB
    short* whoT = (short*)(ws + 4096 + (size_t)(SEQ + 1) * BATCH * HIDDEN * 2);  // 16 MB

    hipMemsetAsync(ws, 0, 256, stream);
    cast_h0<<<BATCH * HIDDEN / 256, 256, 0, stream>>>(status, Hall);
    transpose_cast<<<dim3(VOCAB / 32, HIDDEN / 32), dim3(32, 8), 0, stream>>>(w_ho, whoT);

    rnn_fused<<<NPROD + NCONS, 256, 0, stream>>>(
        Hall, w_hh, w_xh, b_h, X,
        out + (size_t)SEQ * BATCH * VOCAB,   // h_final slot after Y
        bar, prog, whoT, b_o, out);
}

// Round 3
// 2029.674 us; speedup vs baseline: 1.5159x; 1.1973x over previous
//
#include <hip/hip_runtime.h>
#include <hip/hip_bf16.h>
#include <stdint.h>

#define VOCAB 8192
#define HIDDEN 1024
#define BATCH 64
#define SEQ 256

#define NPROD 64      // recurrence workgroups (slot-barrier participants)
#define NCONS 192     // GEMM consumer workgroups
#define GBM 128
#define GBN 128
#define GBK 32
#define NT_M ((SEQ * BATCH) / GBM)   // 128 row-blocks, 2 timesteps each
#define NT_N (VOCAB / GBN)           // 64

#define SLOT_STRIDE 32   // ints: 128 B between slots -> 64 independent L3 lines

typedef __attribute__((ext_vector_type(8))) short short8;
typedef __attribute__((ext_vector_type(4))) float floatx4;

__device__ __forceinline__ short f2bf(float x) {
    __hip_bfloat16 h = __float2bfloat16(x);
    return *reinterpret_cast<short*>(&h);
}

// async global->LDS, 16B per lane. LDS dest must equal (wave-uniform base + lane*16).
__device__ __forceinline__ void load_lds16(const void* g, void* l) {
    __builtin_amdgcn_global_load_lds(
        (const __attribute__((address_space(1))) void*)(uintptr_t)g,
        (__attribute__((address_space(3))) void*)(uint32_t)(uintptr_t)l,
        16, 0, 0);
}

// agent-scope relaxed store/load (sc1): write-through / L2-bypass to the L3
// coherence point. h-stores + slot protocol rely on these; every Hall address
// is single-writer, written before first read, so plain cached reads of Hall
// can never be stale.
__device__ __forceinline__ void st_h(short* p, short v) {
    __hip_atomic_store(p, v, __ATOMIC_RELAXED, __HIP_MEMORY_SCOPE_AGENT);
}
__device__ __forceinline__ void st_slot(int* p, int v) {
    __hip_atomic_store(p, v, __ATOMIC_RELAXED, __HIP_MEMORY_SCOPE_AGENT);
}
__device__ __forceinline__ int ld_slot(const int* p) {
    return __hip_atomic_load(p, __ATOMIC_RELAXED, __HIP_MEMORY_SCOPE_AGENT);
}

// fast tanh: 1 - 2/(e^{2x}+1). exp overflow -> inf -> 1; underflow -> 0 -> -1.
__device__ __forceinline__ float fast_tanh(float x) {
    float e2 = __expf(2.0f * x);
    return 1.0f - 2.0f * __builtin_amdgcn_rcpf(e2 + 1.0f);
}

// ---------------- prep kernels ----------------

__global__ void cast_h0(const float* __restrict__ s, short* __restrict__ d) {
    int i = blockIdx.x * 256 + threadIdx.x;
    d[i] = f2bf(s[i]);
}

// w_ho (1024 x 8192 fp32 row-major) -> whoT (8192 x 1024 bf16 row-major)
__global__ void transpose_cast(const float* __restrict__ who, short* __restrict__ whoT) {
    __shared__ float tile[32][33];
    int n0 = blockIdx.x * 32;   // along VOCAB
    int k0 = blockIdx.y * 32;   // along HIDDEN
    for (int r = threadIdx.y; r < 32; r += 8)
        tile[r][threadIdx.x] = who[(size_t)(k0 + r) * VOCAB + n0 + threadIdx.x];
    __syncthreads();
    for (int r = threadIdx.y; r < 32; r += 8)
        whoT[(size_t)(n0 + r) * HIDDEN + k0 + threadIdx.x] = f2bf(tile[threadIdx.x][r]);
}

// ---------------- fused persistent kernel ----------------
// Slot-array barrier: producer g stores step count into slots[g*32] (own 128B
// line, parallel across L3 slices). Waiters (producers every step; consumers
// per tile-row) detect via ONE wave-parallel sc1 load: lane i reads slot i,
// __all(v >= target). No atomics, no single hot line, detection = store
// visibility (~400cy) + <=1 poll period (~1k cy).
__global__ __launch_bounds__(256) void rnn_fused(
    short* __restrict__ Hall,              // (SEQ+1, 64, 1024) bf16
    const float* __restrict__ w_hh, const float* __restrict__ w_xh,
    const float* __restrict__ b_h, const int* __restrict__ X,
    float* __restrict__ hfin, int* slots,
    const short* __restrict__ whoT, const float* __restrict__ b_o,
    float* __restrict__ C) {
    __shared__ __align__(16) short smem[16 * 1032];  // 33 KB union
    const int tid = threadIdx.x;
    const int w = tid >> 6, lane = tid & 63;

    if (blockIdx.x < NPROD) {
        // ================= producer: h recurrence =================
        short* Bs = smem;
        const int g = blockIdx.x;
        const int q = lane >> 4, r15 = lane & 15;

        // stage w_hh slice once: Bs[c][k] = bf16(w_hh[k][16g+c])
        for (int idx = tid; idx < 16 * 1024; idx += 256) {
            int c = idx & 15, k = idx >> 4;
            Bs[c * 1032 + k] = f2bf(w_hh[(size_t)k * HIDDEN + g * 16 + c]);
        }
        __syncthreads();

        const int jcol = g * 16 + r15;
        const float bh = b_h[jcol];
        int brow[4];
#pragma unroll
        for (int r = 0; r < 4; r++) brow[r] = w * 16 + q * 4 + r;
        const int afr_off = (w * 16 + r15) * HIDDEN + q * 8;

        // xe pipeline: xe = gather for step 0; xr = X indices for step 1
        int xr[4];
#pragma unroll
        for (int r = 0; r < 4; r++) xr[r] = X[brow[r] * SEQ];
        float xe[4];
#pragma unroll
        for (int r = 0; r < 4; r++) xe[r] = w_xh[(size_t)xr[r] * HIDDEN + jcol];
#pragma unroll
        for (int r = 0; r < 4; r++) xr[r] = X[brow[r] * SEQ + 1];

        for (int t = 0; t < SEQ; t++) {
            // issue next step's xe gather FIRST: HBM/L3 latency hides under MFMAs
            float xen[4];
            if (t + 1 < SEQ) {
#pragma unroll
                for (int r = 0; r < 4; r++) xen[r] = w_xh[(size_t)xr[r] * HIDDEN + jcol];
                if (t + 2 < SEQ) {
#pragma unroll
                    for (int r = 0; r < 4; r++) xr[r] = X[brow[r] * SEQ + t + 2];
                }
            }

            const short* Ab = Hall + (size_t)t * (BATCH * HIDDEN) + afr_off;
            floatx4 a0 = {0.f, 0.f, 0.f, 0.f}, a1 = a0, a2 = a0, a3 = a0;
#pragma unroll
            for (int k0 = 0; k0 < HIDDEN; k0 += 128) {
                short8 f0 = *(const short8*)(Ab + k0);
                short8 f1 = *(const short8*)(Ab + k0 + 32);
                short8 f2 = *(const short8*)(Ab + k0 + 64);
                short8 f3 = *(const short8*)(Ab + k0 + 96);
                const short* Bb = &Bs[r15 * 1032 + k0 + q * 8];
                short8 b0 = *(const short8*)(Bb);
                short8 b1 = *(const short8*)(Bb + 32);
                short8 b2 = *(const short8*)(Bb + 64);
                short8 b3 = *(const short8*)(Bb + 96);
                a0 = __builtin_amdgcn_mfma_f32_16x16x32_bf16(f0, b0, a0, 0, 0, 0);
                a1 = __builtin_amdgcn_mfma_f32_16x16x32_bf16(f1, b1, a1, 0, 0, 0);
                a2 = __builtin_amdgcn_mfma_f32_16x16x32_bf16(f2, b2, a2, 0, 0, 0);
                a3 = __builtin_amdgcn_mfma_f32_16x16x32_bf16(f3, b3, a3, 0, 0, 0);
            }
            floatx4 acc = (a0 + a1) + (a2 + a3);

            short* Hnext = Hall + (size_t)(t + 1) * (BATCH * HIDDEN);
#pragma unroll
            for (int r = 0; r < 4; r++) {
                float v = acc[r] + xe[r] + bh;
                float h = fast_tanh(v);
                st_h(&Hnext[brow[r] * HIDDEN + jcol], f2bf(h));
                if (t == SEQ - 1) hfin[brow[r] * HIDDEN + jcol] = h;
            }

            // drain h-stores to L3, then slot-arrive + wave-parallel detect
            asm volatile("s_waitcnt vmcnt(0)" ::: "memory");
            __syncthreads();
            if (tid == 0) st_slot(&slots[g * SLOT_STRIDE], t + 1);
            if (w == 0) {
                for (;;) {
                    int v = ld_slot(&slots[lane * SLOT_STRIDE]);
                    if (__all(v >= t + 1)) break;
                    __builtin_amdgcn_s_sleep(1);
                }
            }
            __syncthreads();
            __builtin_amdgcn_fence(__ATOMIC_ACQUIRE, "workgroup");
#pragma unroll
            for (int r = 0; r < 4; r++) xe[r] = xen[r];
        }
    } else {
        // ================= consumer: C = Hall[1:] @ whoT^T + b_o =================
        short* la = smem;                 // 128x32 bf16 (8 KB)
        short* lb = smem + GBM * GBK;     // 128x32 bf16 (8 KB)
        const short* __restrict__ A = Hall + BATCH * HIDDEN;
        const int cid = (int)blockIdx.x - NPROD;
        const int wave = w;
        const int wm = (wave >> 1) * 64, wn = (wave & 1) * 64;
        const int q = lane >> 4, r15 = lane & 15;
        const int col_l = lane & 15, row_q = (lane >> 4) * 4;

        // stride-NCONS over tiles row-major: tj fixed per wg, ti += 3 -> the
        // required step count grows monotonically.
        for (int n = cid; n < NT_M * NT_N; n += NCONS) {
            const int ti = n / NT_N, tj = n - ti * NT_N;
            const int m0 = ti * GBM, n0 = tj * GBN;

            // tile needs Hall slabs 2ti+1, 2ti+2 -> all slots >= 2ti+2
            const int needed = 2 * ti + 2;
            if (wave == 0) {
                for (;;) {
                    int v = ld_slot(&slots[lane * SLOT_STRIDE]);
                    if (__all(v >= needed)) break;
                    __builtin_amdgcn_s_sleep(16);
                }
            }
            __syncthreads();
            __builtin_amdgcn_fence(__ATOMIC_ACQUIRE, "workgroup");

            floatx4 acc[4][4] = {};
            for (int k0 = 0; k0 < HIDDEN; k0 += GBK) {
#pragma unroll
                for (int i = 0; i < 2; i++) {
                    int c = wave * 128 + i * 64 + lane;   // LDS dest = base + lane*16
                    int row = c >> 2, s = c & 3;
                    int gq = s ^ ((row >> 1) & 3);
                    load_lds16(&A[(size_t)(m0 + row) * HIDDEN + k0 + gq * 8], &la[c * 8]);
                    load_lds16(&whoT[(size_t)(n0 + row) * HIDDEN + k0 + gq * 8], &lb[c * 8]);
                }
                __syncthreads();

                short8 af[4], bf[4];
#pragma unroll
                for (int i = 0; i < 4; i++) {
                    int ra = wm + i * 16 + r15;
                    af[i] = *(const short8*)&la[ra * GBK + (q ^ ((ra >> 1) & 3)) * 8];
                    int rb = wn + i * 16 + r15;
                    bf[i] = *(const short8*)&lb[rb * GBK + (q ^ ((rb >> 1) & 3)) * 8];
                }
#pragma unroll
                for (int i = 0; i < 4; i++)
#pragma unroll
                    for (int jj = 0; jj < 4; jj++)
                        acc[i][jj] = __builtin_amdgcn_mfma_f32_16x16x32_bf16(af[i], bf[jj], acc[i][jj], 0, 0, 0);
                __syncthreads();
            }

#pragma unroll
            for (int i = 0; i < 4; i++) {
#pragma unroll
                for (int jj = 0; jj < 4; jj++) {
                    int col = n0 + wn + jj * 16 + col_l;
                    float bb = b_o[col];
#pragma unroll
                    for (int r = 0; r < 4; r++) {
                        int row = m0 + wm + i * 16 + row_q + r;
                        // nt store: keep C out of L2
                        __builtin_nontemporal_store(acc[i][jj][r] + bb,
                                                    &C[(size_t)row * VOCAB + col]);
                    }
                }
            }
        }
    }
}

// ---------------- launch ----------------

extern "C" void kernel_launch(void* const* d_in, const int* in_sizes, int n_in,
                              void* d_out, int out_size, void* d_ws, size_t ws_size,
                              hipStream_t stream) {
    const int*   X      = (const int*)d_in[0];
    const float* status = (const float*)d_in[1];
    const float* w_xh   = (const float*)d_in[2];
    const float* w_hh   = (const float*)d_in[3];
    const float* w_ho   = (const float*)d_in[4];
    const float* b_h    = (const float*)d_in[5];
    const float* b_o    = (const float*)d_in[6];
    float* out = (float*)d_out;

    char* ws = (char*)d_ws;
    int*   slots = (int*)(ws + 512);                           // 64 slots x 128 B = 8 KB
    short* Hall  = (short*)(ws + 16384);                       // (257,64,1024) bf16 = 33.7 MB
    short* whoT  = (short*)(ws + 16384 + (size_t)(SEQ + 1) * BATCH * HIDDEN * 2);  // 16 MB

    hipMemsetAsync(ws, 0, 16384, stream);
    cast_h0<<<BATCH * HIDDEN / 256, 256, 0, stream>>>(status, Hall);
    transpose_cast<<<dim3(VOCAB / 32, HIDDEN / 32), dim3(32, 8), 0, stream>>>(w_ho, whoT);

    rnn_fused<<<NPROD + NCONS, 256, 0, stream>>>(
        Hall, w_hh, w_xh, b_h, X,
        out + (size_t)SEQ * BATCH * VOCAB,   // h_final slot after Y
        slots, whoT, b_o, out);
}